// Round 1
// baseline (2984.543 us; speedup 1.0000x reference)
//
#include <hip/hip_runtime.h>

// ---------------------------------------------------------------------------
// GRU (T=128, N=512, IN=512, H=512) + LayerNorm, MI355X/gfx950.
// Plan:
//   prep:    cast W_hh -> bf16 in ws, zero group barrier counters
//   gi_gemm: gi = bf16( x @ W_ih^T + b_ih (+ b_hh for r,z gates) )   [MFMA]
//   rec:     persistent kernel, 16 groups x 16 col-blocks, W_hh slice in LDS,
//            per-step h exchange via agent-scope atomics + group barrier
//   ln:      row-wise LayerNorm in-place on d_out
// ---------------------------------------------------------------------------

typedef __attribute__((ext_vector_type(8))) __bf16 bf16x8;
typedef __attribute__((ext_vector_type(4)))  float f32x4;
typedef __attribute__((ext_vector_type(16))) float f32x16;

__device__ __forceinline__ unsigned short f2bf(float f) {
  unsigned u = __builtin_bit_cast(unsigned, f);
  u += 0x7FFFu + ((u >> 16) & 1u);               // RNE
  return (unsigned short)(u >> 16);
}
__device__ __forceinline__ float bf2f(unsigned short h) {
  unsigned u = ((unsigned)h) << 16;
  return __builtin_bit_cast(float, u);
}
__device__ __forceinline__ float sigm(float x) { return 1.0f / (1.0f + __expf(-x)); }
__device__ __forceinline__ float tanh_fast(float x) {
  float t = __expf(2.0f * x);                    // +inf -> 1, 0 -> -1, no NaN
  return 1.0f - 2.0f / (t + 1.0f);
}

// ws layout (bytes)
#define GI_BYTES   ((size_t)65536 * 1536 * 2)          // 201326592
#define WHH_OFF    GI_BYTES
#define WHH_BYTES  ((size_t)1536 * 512 * 2)            // 1572864
#define HB_OFF     (WHH_OFF + WHH_BYTES)
#define HB_BYTES   ((size_t)2 * 512 * 512 * 2)         // 1048576 (ping-pong bf16 h)
#define CNT_OFF    (HB_OFF + HB_BYTES)
#define CNT_BYTES  ((size_t)4096)

// ---------------------------------------------------------------------------
__global__ __launch_bounds__(256) void prep_kernel(const float* __restrict__ whh,
                                                   unsigned short* __restrict__ whh_bf,
                                                   unsigned int* __restrict__ cnt) {
  int i = blockIdx.x * 256 + threadIdx.x;
  for (int j = i; j < 1536 * 512; j += 1024 * 256) whh_bf[j] = f2bf(whh[j]);
  if (blockIdx.x == 0 && threadIdx.x < 16) cnt[threadIdx.x * 64] = 0u;   // 256B apart
}

// ---------------------------------------------------------------------------
// gi GEMM: C[65536 x 1536] = x[65536 x 512] @ W_ih^T, 128x128 tiles, BK=64.
// Both operands row-major with K contiguous -> symmetric staging.
__global__ __launch_bounds__(256) void gi_gemm(const float* __restrict__ x,
                                               const float* __restrict__ wih,
                                               const float* __restrict__ bih,
                                               const float* __restrict__ bhh,
                                               unsigned short* __restrict__ gi) {
  __shared__ unsigned short As[128 * 72];   // stride 72 (ideal-bank for b128 frags)
  __shared__ unsigned short Bs[128 * 72];
  const int tid = threadIdx.x;
  const int rb = blockIdx.x * 128;          // 512 tiles along M
  const int jb = blockIdx.y * 128;          // 12 tiles along N'
  const int wave = tid >> 6, lane = tid & 63;
  const int wm = wave >> 1, wn = wave & 1;  // 2x2 wave grid, 64x64 each
  const int quad = lane >> 4, l16 = lane & 15;

  f32x4 acc[4][4];
  const f32x4 zero4 = {0.f, 0.f, 0.f, 0.f};
  for (int a = 0; a < 4; ++a)
    for (int b = 0; b < 4; ++b) acc[a][b] = zero4;

  for (int kb = 0; kb < 512; kb += 64) {
    __syncthreads();
    // stage A (x) and B (W_ih) f32 -> bf16, 128x64 each
#pragma unroll
    for (int j = 0; j < 8; ++j) {
      int f = tid * 4 + j * 1024;           // flat over [128][64]
      int r = f >> 6, k = f & 63;
      float4 av = *(const float4*)(x + (size_t)(rb + r) * 512 + kb + k);
      ushort4 a4;
      a4.x = f2bf(av.x); a4.y = f2bf(av.y); a4.z = f2bf(av.z); a4.w = f2bf(av.w);
      *(ushort4*)(As + r * 72 + k) = a4;
      float4 bv = *(const float4*)(wih + (size_t)(jb + r) * 512 + kb + k);
      ushort4 b4;
      b4.x = f2bf(bv.x); b4.y = f2bf(bv.y); b4.z = f2bf(bv.z); b4.w = f2bf(bv.w);
      *(ushort4*)(Bs + r * 72 + k) = b4;
    }
    __syncthreads();
#pragma unroll
    for (int kk = 0; kk < 64; kk += 32) {
      bf16x8 af[4], bfr[4];
#pragma unroll
      for (int mi = 0; mi < 4; ++mi)
        af[mi] = *(const bf16x8*)(As + (wm * 64 + mi * 16 + l16) * 72 + kk + quad * 8);
#pragma unroll
      for (int ni = 0; ni < 4; ++ni)
        bfr[ni] = *(const bf16x8*)(Bs + (wn * 64 + ni * 16 + l16) * 72 + kk + quad * 8);
#pragma unroll
      for (int mi = 0; mi < 4; ++mi)
#pragma unroll
        for (int ni = 0; ni < 4; ++ni)
          acc[mi][ni] = __builtin_amdgcn_mfma_f32_16x16x32_bf16(af[mi], bfr[ni],
                                                                acc[mi][ni], 0, 0, 0);
    }
  }
  // epilogue: + b_ih (+ b_hh for r,z cols only; b_hh_n stays inside r* in rec)
#pragma unroll
  for (int ni = 0; ni < 4; ++ni) {
    int jcol = jb + wn * 64 + ni * 16 + l16;
    float bias = bih[jcol] + (jcol < 1024 ? bhh[jcol] : 0.0f);
#pragma unroll
    for (int mi = 0; mi < 4; ++mi) {
#pragma unroll
      for (int reg = 0; reg < 4; ++reg) {
        int grow = rb + wm * 64 + mi * 16 + quad * 4 + reg;   // C row = quad*4+reg
        gi[(size_t)grow * 1536 + jcol] = f2bf(acc[mi][ni][reg] + bias);
      }
    }
  }
}

// ---------------------------------------------------------------------------
// Recurrent kernel: 256 blocks x 192 threads (1/CU). Block (g,c): envs
// [32g,32g+32), h-cols [32c,32c+32). LDS-resident W slice (3 gates x 32 cols).
#define WL_STRIDE 520          // bf16 elems; 1040B rows -> 16B-aligned, ideal banks
#define REC_LDS   149504

__global__ __launch_bounds__(192) void rec_kernel(
    const float* __restrict__ hxs, const float* __restrict__ masks,
    const float* __restrict__ bhh, const unsigned short* __restrict__ gi,
    const unsigned short* __restrict__ whh_bf,
    unsigned short* hb, unsigned int* cnt, float* __restrict__ out) {
  extern __shared__ char smem[];
  unsigned short* Wl = (unsigned short*)smem;              // 96 x 520
  unsigned short* Hl = (unsigned short*)(smem + 99840);    // 32 x 520
  float* gatesL = (float*)(smem + 133120);                 // 3 x 32 x 32
  float* hown = (float*)(smem + 145408);                   // 32 x 32 f32 own h

  const int tid = threadIdx.x;
  const int g = blockIdx.x >> 4;
  const int c = blockIdx.x & 15;
  const int eb = g * 32;
  const int cb = c * 32;
  const int wave = tid >> 6;          // = gate index 0(r) 1(z) 2(n)
  const int lane = tid & 63;
  const int l32 = lane & 31;
  const int lhi = lane >> 5;
  unsigned* hbu = (unsigned*)hb;
  unsigned int* mycnt = cnt + g * 64;

  // load W_hh slice: Wl row r (0..95) = W_hh row (r/32)*512 + cb + (r%32)
  for (int i = tid; i < 6144; i += 192) {
    int idx = i * 8;
    int r = idx >> 9, k = idx & 511;
    int grow = (r >> 5) * 512 + cb + (r & 31);
    uint4 w = *(const uint4*)(whh_bf + (size_t)grow * 512 + k);
    *(uint4*)(Wl + r * WL_STRIDE + k) = w;
  }
  // init h0 (own f32 copy + publish bf16)
  for (int i = tid; i < 512; i += 192) {
    int e = i >> 4, cp = (i & 15) * 2;
    float2 h2 = *(const float2*)(hxs + (size_t)(eb + e) * 512 + cb + cp);
    hown[e * 32 + cp] = h2.x;
    hown[e * 32 + cp + 1] = h2.y;
    unsigned pk = (unsigned)f2bf(h2.x) | ((unsigned)f2bf(h2.y) << 16);
    __hip_atomic_store(hbu + (((unsigned)(eb + e) * 512 + cb + cp) >> 1), pk,
                       __ATOMIC_RELAXED, __HIP_MEMORY_SCOPE_AGENT);
  }

  unsigned bt = 0;
#define GROUP_BARRIER()                                                          \
  do {                                                                           \
    __syncthreads();                                                             \
    bt += 16;                                                                    \
    if (tid == 0) {                                                              \
      __hip_atomic_fetch_add(mycnt, 1u, __ATOMIC_ACQ_REL,                        \
                             __HIP_MEMORY_SCOPE_AGENT);                          \
      int guard = 0;                                                             \
      while (__hip_atomic_load(mycnt, __ATOMIC_ACQUIRE,                          \
                               __HIP_MEMORY_SCOPE_AGENT) < bt) {                 \
        __builtin_amdgcn_s_sleep(2);                                             \
        if (++guard > (1 << 22)) break;                                          \
      }                                                                          \
    }                                                                            \
    __syncthreads();                                                             \
  } while (0)

  GROUP_BARRIER();   // h0 visible group-wide

  for (int t = 0; t < 128; ++t) {
    const unsigned hsrc = (unsigned)(t & 1) * 131072u;        // uints
    const unsigned hdst = (unsigned)((t & 1) ^ 1) * 131072u;
    // stage masked h (bf16) into Hl: 32 envs x 512
    for (int i = tid; i < 4096; i += 192) {
      int e = i >> 7;
      int k4 = (i & 127) * 4;
      float m = masks[t * 512 + eb + e];
      unsigned long long v = __hip_atomic_load(
          (const unsigned long long*)(hbu + hsrc + (((unsigned)(eb + e) * 512 + k4) >> 1)),
          __ATOMIC_RELAXED, __HIP_MEMORY_SCOPE_AGENT);
      ushort4 s;
      s.x = f2bf(bf2f((unsigned short)v) * m);
      s.y = f2bf(bf2f((unsigned short)(v >> 16)) * m);
      s.z = f2bf(bf2f((unsigned short)(v >> 32)) * m);
      s.w = f2bf(bf2f((unsigned short)(v >> 48)) * m);
      *(ushort4*)(Hl + e * WL_STRIDE + k4) = s;
    }
    __syncthreads();

    // gh for gate `wave`: 32 envs x 32 cols, K=512 (32 steps of 32x32x16)
    f32x16 acc = {0.f, 0.f, 0.f, 0.f, 0.f, 0.f, 0.f, 0.f,
                  0.f, 0.f, 0.f, 0.f, 0.f, 0.f, 0.f, 0.f};
    const unsigned short* ap = Hl + l32 * WL_STRIDE + lhi * 8;
    const unsigned short* bp = Wl + (wave * 32 + l32) * WL_STRIDE + lhi * 8;
#pragma unroll
    for (int ks = 0; ks < 32; ++ks) {
      bf16x8 a = *(const bf16x8*)(ap + ks * 16);
      bf16x8 b = *(const bf16x8*)(bp + ks * 16);
      acc = __builtin_amdgcn_mfma_f32_32x32x16_bf16(a, b, acc, 0, 0, 0);
    }
    float* gt = gatesL + wave * 1024;
#pragma unroll
    for (int reg = 0; reg < 16; ++reg) {
      int erow = (reg & 3) + 8 * (reg >> 2) + 4 * lhi;   // measured C/D layout
      gt[erow * 32 + l32] = acc[reg];
    }
    __syncthreads();

    // gates + h update (pairs of cols)
    for (int i = tid; i < 512; i += 192) {
      int e = i >> 4, cp = (i & 15) * 2;
      float m = masks[t * 512 + eb + e];
      size_t gbase = ((size_t)t * 512 + eb + e) * 1536 + cb + cp;
      unsigned gr = *(const unsigned*)(gi + gbase);
      unsigned gz = *(const unsigned*)(gi + gbase + 512);
      unsigned gn = *(const unsigned*)(gi + gbase + 1024);
      float2 bn2 = *(const float2*)(bhh + 1024 + cb + cp);
      int o = e * 32 + cp;
      float r0 = sigm(bf2f((unsigned short)gr) + gatesL[o]);
      float r1 = sigm(bf2f((unsigned short)(gr >> 16)) + gatesL[o + 1]);
      float z0 = sigm(bf2f((unsigned short)gz) + gatesL[1024 + o]);
      float z1 = sigm(bf2f((unsigned short)(gz >> 16)) + gatesL[1024 + o + 1]);
      float n0 = tanh_fast(bf2f((unsigned short)gn) + r0 * (gatesL[2048 + o] + bn2.x));
      float n1 = tanh_fast(bf2f((unsigned short)(gn >> 16)) + r1 * (gatesL[2048 + o + 1] + bn2.y));
      float h0 = hown[o] * m;
      float h1 = hown[o + 1] * m;
      float hn0 = (1.0f - z0) * n0 + z0 * h0;
      float hn1 = (1.0f - z1) * n1 + z1 * h1;
      hown[o] = hn0;
      hown[o + 1] = hn1;
      float2 ov; ov.x = hn0; ov.y = hn1;
      *(float2*)(out + ((size_t)t * 512 + eb + e) * 512 + cb + cp) = ov;
      unsigned pk = (unsigned)f2bf(hn0) | ((unsigned)f2bf(hn1) << 16);
      __hip_atomic_store(hbu + hdst + (((unsigned)(eb + e) * 512 + cb + cp) >> 1), pk,
                         __ATOMIC_RELAXED, __HIP_MEMORY_SCOPE_AGENT);
      if (t == 127) {
        *(float2*)(out + (size_t)33554432 + (size_t)(eb + e) * 512 + cb + cp) = ov;
      }
    }
    GROUP_BARRIER();   // publishes of step t visible before staging t+1
  }
#undef GROUP_BARRIER
}

// ---------------------------------------------------------------------------
// In-place LayerNorm over 65536 rows of 512 (one wave per row).
__global__ __launch_bounds__(256) void ln_kernel(float* __restrict__ out,
                                                 const float* __restrict__ lnw,
                                                 const float* __restrict__ lnb) {
  int row = blockIdx.x * 4 + (threadIdx.x >> 6);
  int lane = threadIdx.x & 63;
  float* p = out + (size_t)row * 512 + lane * 8;
  float4 v0 = *(float4*)p;
  float4 v1 = *(float4*)(p + 4);
  float s = v0.x + v0.y + v0.z + v0.w + v1.x + v1.y + v1.z + v1.w;
  float q = v0.x * v0.x + v0.y * v0.y + v0.z * v0.z + v0.w * v0.w +
            v1.x * v1.x + v1.y * v1.y + v1.z * v1.z + v1.w * v1.w;
#pragma unroll
  for (int m = 1; m < 64; m <<= 1) {
    s += __shfl_xor(s, m, 64);
    q += __shfl_xor(q, m, 64);
  }
  float mean = s * (1.0f / 512.0f);
  float var = q * (1.0f / 512.0f) - mean * mean;
  float rstd = rsqrtf(fmaxf(var, 0.0f) + 1e-5f);
  float4 w0 = *(const float4*)(lnw + lane * 8);
  float4 w1 = *(const float4*)(lnw + lane * 8 + 4);
  float4 b0 = *(const float4*)(lnb + lane * 8);
  float4 b1 = *(const float4*)(lnb + lane * 8 + 4);
  v0.x = (v0.x - mean) * rstd * w0.x + b0.x;
  v0.y = (v0.y - mean) * rstd * w0.y + b0.y;
  v0.z = (v0.z - mean) * rstd * w0.z + b0.z;
  v0.w = (v0.w - mean) * rstd * w0.w + b0.w;
  v1.x = (v1.x - mean) * rstd * w1.x + b1.x;
  v1.y = (v1.y - mean) * rstd * w1.y + b1.y;
  v1.z = (v1.z - mean) * rstd * w1.z + b1.z;
  v1.w = (v1.w - mean) * rstd * w1.w + b1.w;
  *(float4*)p = v0;
  *(float4*)(p + 4) = v1;
}

// ---------------------------------------------------------------------------
extern "C" void kernel_launch(void* const* d_in, const int* in_sizes, int n_in,
                              void* d_out, int out_size, void* d_ws, size_t ws_size,
                              hipStream_t stream) {
  const float* x    = (const float*)d_in[0];
  const float* hxs  = (const float*)d_in[1];
  const float* masks= (const float*)d_in[2];
  const float* wih  = (const float*)d_in[3];
  const float* whh  = (const float*)d_in[4];
  const float* bih  = (const float*)d_in[5];
  const float* bhh  = (const float*)d_in[6];
  const float* lnw  = (const float*)d_in[7];
  const float* lnb  = (const float*)d_in[8];
  float* out = (float*)d_out;
  char* ws = (char*)d_ws;

  unsigned short* gi     = (unsigned short*)ws;
  unsigned short* whh_bf = (unsigned short*)(ws + WHH_OFF);
  unsigned short* hb     = (unsigned short*)(ws + HB_OFF);
  unsigned int*   cnt    = (unsigned int*)(ws + CNT_OFF);

  prep_kernel<<<1024, 256, 0, stream>>>(whh, whh_bf, cnt);
  gi_gemm<<<dim3(512, 12), 256, 0, stream>>>(x, wih, bih, bhh, gi);
  hipFuncSetAttribute((const void*)rec_kernel,
                      hipFuncAttributeMaxDynamicSharedMemorySize, REC_LDS);
  rec_kernel<<<256, 192, REC_LDS, stream>>>(hxs, masks, bhh, gi, whh_bf, hb, cnt, out);
  ln_kernel<<<16384, 256, 0, stream>>>(out, lnw, lnb);
}

// Round 2
// 2047.762 us; speedup vs baseline: 1.4575x; 1.4575x over previous
//
#include <hip/hip_runtime.h>

// ---------------------------------------------------------------------------
// GRU (T=128, N=512, IN=512, H=512) + LayerNorm, MI355X/gfx950.
// Plan:
//   prep:    cast W_hh -> bf16 in ws, zero group barrier counters
//   gi_gemm: gi = bf16( x @ W_ih^T + b_ih (+ b_hh for r,z gates) )   [MFMA]
//   rec:     persistent kernel, 16 groups x 16 col-blocks, W_hh slice in LDS,
//            per-step h exchange via RELAXED agent-scope atomics (sc1 ->
//            LLC-coherent across XCDs) + relaxed counter barrier.
//            NOTE: no acquire/release on the barrier! acq/rel at agent scope
//            lowers to buffer_inv / buffer_wbl2 (full per-XCD L2 maintenance)
//            which at 16 blocks x 128 steps serializes at L2 and nukes
//            caching for the whole XCD (R1: 19.3 us/step, FETCH 463 MB).
//            Ordering is already guaranteed: __syncthreads() emits
//            s_waitcnt vmcnt(0) for every wave before s_barrier, so all sc1
//            h-stores are device-visible before tid0 bumps the counter.
//   ln:      row-wise LayerNorm in-place on d_out
// ---------------------------------------------------------------------------

typedef __attribute__((ext_vector_type(8))) __bf16 bf16x8;
typedef __attribute__((ext_vector_type(4)))  float f32x4;
typedef __attribute__((ext_vector_type(16))) float f32x16;

__device__ __forceinline__ unsigned short f2bf(float f) {
  unsigned u = __builtin_bit_cast(unsigned, f);
  u += 0x7FFFu + ((u >> 16) & 1u);               // RNE
  return (unsigned short)(u >> 16);
}
__device__ __forceinline__ float bf2f(unsigned short h) {
  unsigned u = ((unsigned)h) << 16;
  return __builtin_bit_cast(float, u);
}
__device__ __forceinline__ float sigm(float x) { return 1.0f / (1.0f + __expf(-x)); }
__device__ __forceinline__ float tanh_fast(float x) {
  float t = __expf(2.0f * x);                    // +inf -> 1, 0 -> -1, no NaN
  return 1.0f - 2.0f / (t + 1.0f);
}

// ws layout (bytes)
#define GI_BYTES   ((size_t)65536 * 1536 * 2)          // 201326592
#define WHH_OFF    GI_BYTES
#define WHH_BYTES  ((size_t)1536 * 512 * 2)            // 1572864
#define HB_OFF     (WHH_OFF + WHH_BYTES)
#define HB_BYTES   ((size_t)2 * 512 * 512 * 2)         // 1048576 (ping-pong bf16 h)
#define CNT_OFF    (HB_OFF + HB_BYTES)
#define CNT_BYTES  ((size_t)4096)

// ---------------------------------------------------------------------------
__global__ __launch_bounds__(256) void prep_kernel(const float* __restrict__ whh,
                                                   unsigned short* __restrict__ whh_bf,
                                                   unsigned int* __restrict__ cnt) {
  int i = blockIdx.x * 256 + threadIdx.x;
  for (int j = i; j < 1536 * 512; j += 1024 * 256) whh_bf[j] = f2bf(whh[j]);
  if (blockIdx.x == 0 && threadIdx.x < 16) cnt[threadIdx.x * 64] = 0u;   // 256B apart
}

// ---------------------------------------------------------------------------
// gi GEMM: C[65536 x 1536] = x[65536 x 512] @ W_ih^T, 128x128 tiles, BK=64.
// Both operands row-major with K contiguous -> symmetric staging.
__global__ __launch_bounds__(256) void gi_gemm(const float* __restrict__ x,
                                               const float* __restrict__ wih,
                                               const float* __restrict__ bih,
                                               const float* __restrict__ bhh,
                                               unsigned short* __restrict__ gi) {
  __shared__ unsigned short As[128 * 72];   // stride 72 (ideal-bank for b128 frags)
  __shared__ unsigned short Bs[128 * 72];
  const int tid = threadIdx.x;
  const int rb = blockIdx.x * 128;          // 512 tiles along M
  const int jb = blockIdx.y * 128;          // 12 tiles along N'
  const int wave = tid >> 6, lane = tid & 63;
  const int wm = wave >> 1, wn = wave & 1;  // 2x2 wave grid, 64x64 each
  const int quad = lane >> 4, l16 = lane & 15;

  f32x4 acc[4][4];
  const f32x4 zero4 = {0.f, 0.f, 0.f, 0.f};
  for (int a = 0; a < 4; ++a)
    for (int b = 0; b < 4; ++b) acc[a][b] = zero4;

  for (int kb = 0; kb < 512; kb += 64) {
    __syncthreads();
    // stage A (x) and B (W_ih) f32 -> bf16, 128x64 each
#pragma unroll
    for (int j = 0; j < 8; ++j) {
      int f = tid * 4 + j * 1024;           // flat over [128][64]
      int r = f >> 6, k = f & 63;
      float4 av = *(const float4*)(x + (size_t)(rb + r) * 512 + kb + k);
      ushort4 a4;
      a4.x = f2bf(av.x); a4.y = f2bf(av.y); a4.z = f2bf(av.z); a4.w = f2bf(av.w);
      *(ushort4*)(As + r * 72 + k) = a4;
      float4 bv = *(const float4*)(wih + (size_t)(jb + r) * 512 + kb + k);
      ushort4 b4;
      b4.x = f2bf(bv.x); b4.y = f2bf(bv.y); b4.z = f2bf(bv.z); b4.w = f2bf(bv.w);
      *(ushort4*)(Bs + r * 72 + k) = b4;
    }
    __syncthreads();
#pragma unroll
    for (int kk = 0; kk < 64; kk += 32) {
      bf16x8 af[4], bfr[4];
#pragma unroll
      for (int mi = 0; mi < 4; ++mi)
        af[mi] = *(const bf16x8*)(As + (wm * 64 + mi * 16 + l16) * 72 + kk + quad * 8);
#pragma unroll
      for (int ni = 0; ni < 4; ++ni)
        bfr[ni] = *(const bf16x8*)(Bs + (wn * 64 + ni * 16 + l16) * 72 + kk + quad * 8);
#pragma unroll
      for (int mi = 0; mi < 4; ++mi)
#pragma unroll
        for (int ni = 0; ni < 4; ++ni)
          acc[mi][ni] = __builtin_amdgcn_mfma_f32_16x16x32_bf16(af[mi], bfr[ni],
                                                                acc[mi][ni], 0, 0, 0);
    }
  }
  // epilogue: + b_ih (+ b_hh for r,z cols only; b_hh_n stays inside r* in rec)
#pragma unroll
  for (int ni = 0; ni < 4; ++ni) {
    int jcol = jb + wn * 64 + ni * 16 + l16;
    float bias = bih[jcol] + (jcol < 1024 ? bhh[jcol] : 0.0f);
#pragma unroll
    for (int mi = 0; mi < 4; ++mi) {
#pragma unroll
      for (int reg = 0; reg < 4; ++reg) {
        int grow = rb + wm * 64 + mi * 16 + quad * 4 + reg;   // C row = quad*4+reg
        gi[(size_t)grow * 1536 + jcol] = f2bf(acc[mi][ni][reg] + bias);
      }
    }
  }
}

// ---------------------------------------------------------------------------
// Recurrent kernel: 256 blocks x 192 threads (1/CU). Block (g,c): envs
// [32g,32g+32), h-cols [32c,32c+32). LDS-resident W slice (3 gates x 32 cols).
#define WL_STRIDE 520          // bf16 elems; 1040B rows -> 16B-aligned, ideal banks
#define REC_LDS   149504

__global__ __launch_bounds__(192) void rec_kernel(
    const float* __restrict__ hxs, const float* __restrict__ masks,
    const float* __restrict__ bhh, const unsigned short* __restrict__ gi,
    const unsigned short* __restrict__ whh_bf,
    unsigned short* hb, unsigned int* cnt, float* __restrict__ out) {
  extern __shared__ char smem[];
  unsigned short* Wl = (unsigned short*)smem;              // 96 x 520
  unsigned short* Hl = (unsigned short*)(smem + 99840);    // 32 x 520
  float* gatesL = (float*)(smem + 133120);                 // 3 x 32 x 32
  float* hown = (float*)(smem + 145408);                   // 32 x 32 f32 own h

  const int tid = threadIdx.x;
  const int g = blockIdx.x >> 4;
  const int c = blockIdx.x & 15;
  const int eb = g * 32;
  const int cb = c * 32;
  const int wave = tid >> 6;          // = gate index 0(r) 1(z) 2(n)
  const int lane = tid & 63;
  const int l32 = lane & 31;
  const int lhi = lane >> 5;
  unsigned* hbu = (unsigned*)hb;
  unsigned int* mycnt = cnt + g * 64;

  // load W_hh slice: Wl row r (0..95) = W_hh row (r/32)*512 + cb + (r%32)
  for (int i = tid; i < 6144; i += 192) {
    int idx = i * 8;
    int r = idx >> 9, k = idx & 511;
    int grow = (r >> 5) * 512 + cb + (r & 31);
    uint4 w = *(const uint4*)(whh_bf + (size_t)grow * 512 + k);
    *(uint4*)(Wl + r * WL_STRIDE + k) = w;
  }
  // init h0 (own f32 copy + publish bf16)
  for (int i = tid; i < 512; i += 192) {
    int e = i >> 4, cp = (i & 15) * 2;
    float2 h2 = *(const float2*)(hxs + (size_t)(eb + e) * 512 + cb + cp);
    hown[e * 32 + cp] = h2.x;
    hown[e * 32 + cp + 1] = h2.y;
    unsigned pk = (unsigned)f2bf(h2.x) | ((unsigned)f2bf(h2.y) << 16);
    __hip_atomic_store(hbu + (((unsigned)(eb + e) * 512 + cb + cp) >> 1), pk,
                       __ATOMIC_RELAXED, __HIP_MEMORY_SCOPE_AGENT);
  }

  unsigned bt = 0;
  // RELAXED-only group barrier: no buffer_inv / buffer_wbl2 L2 maintenance.
  // __syncthreads() already drains vmcnt for every wave (sc1 stores device-
  // visible) before tid0 publishes the arrival.
#define GROUP_BARRIER()                                                          \
  do {                                                                           \
    __syncthreads();                                                             \
    bt += 16;                                                                    \
    if (tid == 0) {                                                              \
      __hip_atomic_fetch_add(mycnt, 1u, __ATOMIC_RELAXED,                        \
                             __HIP_MEMORY_SCOPE_AGENT);                          \
      int guard = 0;                                                             \
      while (__hip_atomic_load(mycnt, __ATOMIC_RELAXED,                          \
                               __HIP_MEMORY_SCOPE_AGENT) < bt) {                 \
        __builtin_amdgcn_s_sleep(1);                                             \
        if (++guard > (1 << 20)) break;                                          \
      }                                                                          \
    }                                                                            \
    __syncthreads();                                                             \
  } while (0)

  GROUP_BARRIER();   // h0 visible group-wide

  for (int t = 0; t < 128; ++t) {
    const unsigned hsrc = (unsigned)(t & 1) * 131072u;        // uints
    const unsigned hdst = (unsigned)((t & 1) ^ 1) * 131072u;
    // stage masked h (bf16) into Hl: 32 envs x 512
    for (int i = tid; i < 4096; i += 192) {
      int e = i >> 7;
      int k4 = (i & 127) * 4;
      float m = masks[t * 512 + eb + e];
      unsigned long long v = __hip_atomic_load(
          (const unsigned long long*)(hbu + hsrc + (((unsigned)(eb + e) * 512 + k4) >> 1)),
          __ATOMIC_RELAXED, __HIP_MEMORY_SCOPE_AGENT);
      ushort4 s;
      s.x = f2bf(bf2f((unsigned short)v) * m);
      s.y = f2bf(bf2f((unsigned short)(v >> 16)) * m);
      s.z = f2bf(bf2f((unsigned short)(v >> 32)) * m);
      s.w = f2bf(bf2f((unsigned short)(v >> 48)) * m);
      *(ushort4*)(Hl + e * WL_STRIDE + k4) = s;
    }
    __syncthreads();

    // gh for gate `wave`: 32 envs x 32 cols, K=512 (32 steps of 32x32x16)
    f32x16 acc = {0.f, 0.f, 0.f, 0.f, 0.f, 0.f, 0.f, 0.f,
                  0.f, 0.f, 0.f, 0.f, 0.f, 0.f, 0.f, 0.f};
    const unsigned short* ap = Hl + l32 * WL_STRIDE + lhi * 8;
    const unsigned short* bp = Wl + (wave * 32 + l32) * WL_STRIDE + lhi * 8;
#pragma unroll
    for (int ks = 0; ks < 32; ++ks) {
      bf16x8 a = *(const bf16x8*)(ap + ks * 16);
      bf16x8 b = *(const bf16x8*)(bp + ks * 16);
      acc = __builtin_amdgcn_mfma_f32_32x32x16_bf16(a, b, acc, 0, 0, 0);
    }
    float* gt = gatesL + wave * 1024;
#pragma unroll
    for (int reg = 0; reg < 16; ++reg) {
      int erow = (reg & 3) + 8 * (reg >> 2) + 4 * lhi;   // measured C/D layout
      gt[erow * 32 + l32] = acc[reg];
    }
    __syncthreads();

    // gates + h update (pairs of cols)
    for (int i = tid; i < 512; i += 192) {
      int e = i >> 4, cp = (i & 15) * 2;
      float m = masks[t * 512 + eb + e];
      size_t gbase = ((size_t)t * 512 + eb + e) * 1536 + cb + cp;
      unsigned gr = *(const unsigned*)(gi + gbase);
      unsigned gz = *(const unsigned*)(gi + gbase + 512);
      unsigned gn = *(const unsigned*)(gi + gbase + 1024);
      float2 bn2 = *(const float2*)(bhh + 1024 + cb + cp);
      int o = e * 32 + cp;
      float r0 = sigm(bf2f((unsigned short)gr) + gatesL[o]);
      float r1 = sigm(bf2f((unsigned short)(gr >> 16)) + gatesL[o + 1]);
      float z0 = sigm(bf2f((unsigned short)gz) + gatesL[1024 + o]);
      float z1 = sigm(bf2f((unsigned short)(gz >> 16)) + gatesL[1024 + o + 1]);
      float n0 = tanh_fast(bf2f((unsigned short)gn) + r0 * (gatesL[2048 + o] + bn2.x));
      float n1 = tanh_fast(bf2f((unsigned short)(gn >> 16)) + r1 * (gatesL[2048 + o + 1] + bn2.y));
      float h0 = hown[o] * m;
      float h1 = hown[o + 1] * m;
      float hn0 = (1.0f - z0) * n0 + z0 * h0;
      float hn1 = (1.0f - z1) * n1 + z1 * h1;
      hown[o] = hn0;
      hown[o + 1] = hn1;
      float2 ov; ov.x = hn0; ov.y = hn1;
      *(float2*)(out + ((size_t)t * 512 + eb + e) * 512 + cb + cp) = ov;
      unsigned pk = (unsigned)f2bf(hn0) | ((unsigned)f2bf(hn1) << 16);
      __hip_atomic_store(hbu + hdst + (((unsigned)(eb + e) * 512 + cb + cp) >> 1), pk,
                         __ATOMIC_RELAXED, __HIP_MEMORY_SCOPE_AGENT);
      if (t == 127) {
        *(float2*)(out + (size_t)33554432 + (size_t)(eb + e) * 512 + cb + cp) = ov;
      }
    }
    GROUP_BARRIER();   // publishes of step t visible before staging t+1
  }
#undef GROUP_BARRIER
}

// ---------------------------------------------------------------------------
// In-place LayerNorm over 65536 rows of 512 (one wave per row).
__global__ __launch_bounds__(256) void ln_kernel(float* __restrict__ out,
                                                 const float* __restrict__ lnw,
                                                 const float* __restrict__ lnb) {
  int row = blockIdx.x * 4 + (threadIdx.x >> 6);
  int lane = threadIdx.x & 63;
  float* p = out + (size_t)row * 512 + lane * 8;
  float4 v0 = *(float4*)p;
  float4 v1 = *(float4*)(p + 4);
  float s = v0.x + v0.y + v0.z + v0.w + v1.x + v1.y + v1.z + v1.w;
  float q = v0.x * v0.x + v0.y * v0.y + v0.z * v0.z + v0.w * v0.w +
            v1.x * v1.x + v1.y * v1.y + v1.z * v1.z + v1.w * v1.w;
#pragma unroll
  for (int m = 1; m < 64; m <<= 1) {
    s += __shfl_xor(s, m, 64);
    q += __shfl_xor(q, m, 64);
  }
  float mean = s * (1.0f / 512.0f);
  float var = q * (1.0f / 512.0f) - mean * mean;
  float rstd = rsqrtf(fmaxf(var, 0.0f) + 1e-5f);
  float4 w0 = *(const float4*)(lnw + lane * 8);
  float4 w1 = *(const float4*)(lnw + lane * 8 + 4);
  float4 b0 = *(const float4*)(lnb + lane * 8);
  float4 b1 = *(const float4*)(lnb + lane * 8 + 4);
  v0.x = (v0.x - mean) * rstd * w0.x + b0.x;
  v0.y = (v0.y - mean) * rstd * w0.y + b0.y;
  v0.z = (v0.z - mean) * rstd * w0.z + b0.z;
  v0.w = (v0.w - mean) * rstd * w0.w + b0.w;
  v1.x = (v1.x - mean) * rstd * w1.x + b1.x;
  v1.y = (v1.y - mean) * rstd * w1.y + b1.y;
  v1.z = (v1.z - mean) * rstd * w1.z + b1.z;
  v1.w = (v1.w - mean) * rstd * w1.w + b1.w;
  *(float4*)p = v0;
  *(float4*)(p + 4) = v1;
}

// ---------------------------------------------------------------------------
extern "C" void kernel_launch(void* const* d_in, const int* in_sizes, int n_in,
                              void* d_out, int out_size, void* d_ws, size_t ws_size,
                              hipStream_t stream) {
  const float* x    = (const float*)d_in[0];
  const float* hxs  = (const float*)d_in[1];
  const float* masks= (const float*)d_in[2];
  const float* wih  = (const float*)d_in[3];
  const float* whh  = (const float*)d_in[4];
  const float* bih  = (const float*)d_in[5];
  const float* bhh  = (const float*)d_in[6];
  const float* lnw  = (const float*)d_in[7];
  const float* lnb  = (const float*)d_in[8];
  float* out = (float*)d_out;
  char* ws = (char*)d_ws;

  unsigned short* gi     = (unsigned short*)ws;
  unsigned short* whh_bf = (unsigned short*)(ws + WHH_OFF);
  unsigned short* hb     = (unsigned short*)(ws + HB_OFF);
  unsigned int*   cnt    = (unsigned int*)(ws + CNT_OFF);

  prep_kernel<<<1024, 256, 0, stream>>>(whh, whh_bf, cnt);
  gi_gemm<<<dim3(512, 12), 256, 0, stream>>>(x, wih, bih, bhh, gi);
  hipFuncSetAttribute((const void*)rec_kernel,
                      hipFuncAttributeMaxDynamicSharedMemorySize, REC_LDS);
  rec_kernel<<<256, 192, REC_LDS, stream>>>(hxs, masks, bhh, gi, whh_bf, hb, cnt, out);
  ln_kernel<<<16384, 256, 0, stream>>>(out, lnw, lnb);
}

// Round 3
// 1137.800 us; speedup vs baseline: 2.6231x; 1.7998x over previous
//
#include <hip/hip_runtime.h>

// ---------------------------------------------------------------------------
// GRU (T=128, N=512, IN=512, H=512) + LayerNorm, MI355X/gfx950.
//   prep:    cast W_hh -> bf16, zero barrier flags
//   gi_gemm: gi = bf16( x @ W_ih^T + b_ih (+ b_hh for r,z) )   [MFMA]
//   rec:     128 blocks x 384 thr (32 envs x 64 cols each), W_hh slice in
//            VGPRs, h exchange via global_load_lds (sc0|sc1 -> coherence
//            point) + per-block flag barrier (fan-in 8). R2 lesson: atomic
//            loads never pipeline (LLVM won't reorder atomics) -> 22 exposed
//            LLC round trips/step; LDS-DMA issues back-to-back.
//   ln:      row-wise LayerNorm in-place on d_out
// ---------------------------------------------------------------------------

typedef __attribute__((ext_vector_type(8))) __bf16 bf16x8;
typedef __attribute__((ext_vector_type(4)))  float f32x4;
typedef __attribute__((ext_vector_type(16))) float f32x16;

__device__ __forceinline__ unsigned short f2bf(float f) {
  unsigned u = __builtin_bit_cast(unsigned, f);
  u += 0x7FFFu + ((u >> 16) & 1u);               // RNE
  return (unsigned short)(u >> 16);
}
__device__ __forceinline__ float bf2f(unsigned short h) {
  unsigned u = ((unsigned)h) << 16;
  return __builtin_bit_cast(float, u);
}
__device__ __forceinline__ float sigm(float x) { return 1.0f / (1.0f + __expf(-x)); }
__device__ __forceinline__ float tanh_fast(float x) {
  float t = __expf(2.0f * x);                    // +inf -> 1, 0 -> -1, no NaN
  return 1.0f - 2.0f / (t + 1.0f);
}

// ws layout (bytes)
#define GI_BYTES   ((size_t)65536 * 1536 * 2)          // 201326592
#define WHH_OFF    GI_BYTES
#define WHH_BYTES  ((size_t)1536 * 512 * 2)            // 1572864
#define HB_OFF     (WHH_OFF + WHH_BYTES)
#define HB_BYTES   ((size_t)2 * 512 * 512 * 2)         // ping-pong bf16 h
#define CNT_OFF    (HB_OFF + HB_BYTES)

// ---------------------------------------------------------------------------
__global__ __launch_bounds__(256) void prep_kernel(const float* __restrict__ whh,
                                                   unsigned short* __restrict__ whh_bf,
                                                   unsigned int* __restrict__ cnt) {
  int i = blockIdx.x * 256 + threadIdx.x;
  for (int j = i; j < 1536 * 512; j += 1024 * 256) whh_bf[j] = f2bf(whh[j]);
  if (i < 2048) cnt[i] = 0u;      // 128 flags, 64B apart
}

// ---------------------------------------------------------------------------
// gi GEMM: C[65536 x 1536] = x[65536 x 512] @ W_ih^T, 128x128 tiles, BK=64.
__global__ __launch_bounds__(256) void gi_gemm(const float* __restrict__ x,
                                               const float* __restrict__ wih,
                                               const float* __restrict__ bih,
                                               const float* __restrict__ bhh,
                                               unsigned short* __restrict__ gi) {
  __shared__ unsigned short As[128 * 72];
  __shared__ unsigned short Bs[128 * 72];
  const int tid = threadIdx.x;
  const int rb = blockIdx.x * 128;
  const int jb = blockIdx.y * 128;
  const int wave = tid >> 6, lane = tid & 63;
  const int wm = wave >> 1, wn = wave & 1;
  const int quad = lane >> 4, l16 = lane & 15;

  f32x4 acc[4][4];
  const f32x4 zero4 = {0.f, 0.f, 0.f, 0.f};
  for (int a = 0; a < 4; ++a)
    for (int b = 0; b < 4; ++b) acc[a][b] = zero4;

  for (int kb = 0; kb < 512; kb += 64) {
    __syncthreads();
#pragma unroll
    for (int j = 0; j < 8; ++j) {
      int f = tid * 4 + j * 1024;
      int r = f >> 6, k = f & 63;
      float4 av = *(const float4*)(x + (size_t)(rb + r) * 512 + kb + k);
      ushort4 a4;
      a4.x = f2bf(av.x); a4.y = f2bf(av.y); a4.z = f2bf(av.z); a4.w = f2bf(av.w);
      *(ushort4*)(As + r * 72 + k) = a4;
      float4 bv = *(const float4*)(wih + (size_t)(jb + r) * 512 + kb + k);
      ushort4 b4;
      b4.x = f2bf(bv.x); b4.y = f2bf(bv.y); b4.z = f2bf(bv.z); b4.w = f2bf(bv.w);
      *(ushort4*)(Bs + r * 72 + k) = b4;
    }
    __syncthreads();
#pragma unroll
    for (int kk = 0; kk < 64; kk += 32) {
      bf16x8 af[4], bfr[4];
#pragma unroll
      for (int mi = 0; mi < 4; ++mi)
        af[mi] = *(const bf16x8*)(As + (wm * 64 + mi * 16 + l16) * 72 + kk + quad * 8);
#pragma unroll
      for (int ni = 0; ni < 4; ++ni)
        bfr[ni] = *(const bf16x8*)(Bs + (wn * 64 + ni * 16 + l16) * 72 + kk + quad * 8);
#pragma unroll
      for (int mi = 0; mi < 4; ++mi)
#pragma unroll
        for (int ni = 0; ni < 4; ++ni)
          acc[mi][ni] = __builtin_amdgcn_mfma_f32_16x16x32_bf16(af[mi], bfr[ni],
                                                                acc[mi][ni], 0, 0, 0);
    }
  }
#pragma unroll
  for (int ni = 0; ni < 4; ++ni) {
    int jcol = jb + wn * 64 + ni * 16 + l16;
    float bias = bih[jcol] + (jcol < 1024 ? bhh[jcol] : 0.0f);
#pragma unroll
    for (int mi = 0; mi < 4; ++mi) {
#pragma unroll
      for (int reg = 0; reg < 4; ++reg) {
        int grow = rb + wm * 64 + mi * 16 + quad * 4 + reg;
        gi[(size_t)grow * 1536 + jcol] = f2bf(acc[mi][ni][reg] + bias);
      }
    }
  }
}

// ---------------------------------------------------------------------------
// Recurrent kernel: 128 blocks x 384 threads. Block (g = bid>>3, c = bid&7):
// envs [32g,32g+32), h-cols [64c,64c+64). 6 waves: gate = w>>1, half = w&1,
// each wave computes 32 envs x 32 cols via 32x32x16 MFMA, W slice in VGPRs.
#define HL_STRIDE 520          // bf16 elems; 1040 B rows = odd multiple of 16B

__global__ __launch_bounds__(384, 2) void rec_kernel(
    const float* __restrict__ hxs, const float* __restrict__ masks,
    const float* __restrict__ bhh, const unsigned short* __restrict__ gi,
    const unsigned short* __restrict__ whh_bf,
    unsigned short* hb, unsigned int* cnt, float* __restrict__ out) {
  __shared__ unsigned short Hl[32 * HL_STRIDE];   // 33280 B
  __shared__ float gatesL[3 * 32 * 64];           // 24576 B

  const int tid = threadIdx.x;
  const int bid = blockIdx.x;
  const int g = bid >> 3;
  const int eb = g * 32;
  const int cb = (bid & 7) * 64;
  const int wave = tid >> 6;          // 0..5
  const int lane = tid & 63;
  const int l32 = lane & 31;
  const int lhi = lane >> 5;
  const int gate = wave >> 1;         // 0(r) 1(z) 2(n)
  const int half = wave & 1;          // col half within 64
  unsigned* hbu = (unsigned*)hb;

  // W_hh slice -> VGPRs: wave's rows = gate*512 + cb + half*32 + l32, K=512
  bf16x8 wreg[32];
  {
    const unsigned short* wb =
        whh_bf + (((size_t)(gate * 512 + cb + half * 32 + l32)) << 9) + lhi * 8;
#pragma unroll
    for (int ks = 0; ks < 32; ++ks) wreg[ks] = *(const bf16x8*)(wb + (ks << 4));
  }

  // own-h registers + loop-invariant b_hh_n prefetch; publish h0 (bf16)
  float hr0[3], hr1[3];
  float bn0[3], bn1[3];
#pragma unroll
  for (int j = 0; j < 3; ++j) {
    int idx = tid + j * 384;
    if (idx < 1024) {
      int e = idx >> 5, cp = (idx & 31) << 1;
      float2 h2 = *(const float2*)(hxs + (size_t)(eb + e) * 512 + cb + cp);
      hr0[j] = h2.x; hr1[j] = h2.y;
      float2 bn2 = *(const float2*)(bhh + 1024 + cb + cp);
      bn0[j] = bn2.x; bn1[j] = bn2.y;
      unsigned pk = (unsigned)f2bf(h2.x) | ((unsigned)f2bf(h2.y) << 16);
      __hip_atomic_store(hbu + ((((unsigned)(eb + e) << 9) + cb + cp) >> 1), pk,
                         __ATOMIC_RELAXED, __HIP_MEMORY_SCOPE_AGENT);
    }
  }

  unsigned bt = 0;
  unsigned int* myflag = cnt + bid * 16;            // 64B apart
  unsigned int* pollbase = cnt + (g * 8) * 16;

#define GROUP_BARRIER()                                                          \
  do {                                                                           \
    __syncthreads();            /* drains all waves' publishes (vmcnt 0) */      \
    bt += 1;                                                                     \
    if (tid == 0)                                                                \
      __hip_atomic_store(myflag, bt, __ATOMIC_RELAXED, __HIP_MEMORY_SCOPE_AGENT);\
    if (tid < 64) {                                                              \
      unsigned int* fp = pollbase + (lane & 7) * 16;                             \
      int guard = 0;                                                             \
      for (;;) {                                                                 \
        unsigned v = __hip_atomic_load(fp, __ATOMIC_RELAXED,                     \
                                       __HIP_MEMORY_SCOPE_AGENT);                \
        if (__all(v >= bt)) break;                                               \
        __builtin_amdgcn_s_sleep(1);                                             \
        if (++guard > (1 << 20)) break;                                          \
      }                                                                          \
    }                                                                            \
    __syncthreads();                                                             \
  } while (0)

  GROUP_BARRIER();   // h0 visible group-wide

  for (int t = 0; t < 128; ++t) {
    const unsigned hsrc = (unsigned)(t & 1) * 131072u;        // u32 units
    const unsigned hdst = (unsigned)((t & 1) ^ 1) * 131072u;

    // stage h rows via LDS-DMA (sc0|sc1 = 0x11: read at coherence point),
    // one instruction per 1 KB env-row; pipelined, drained by S1.
    for (int e = wave; e < 32; e += 6) {
      const unsigned* gp = hbu + hsrc + ((unsigned)(eb + e) << 8) + (lane << 2);
      __builtin_amdgcn_global_load_lds(
          (const __attribute__((address_space(1))) unsigned*)gp,
          (__attribute__((address_space(3))) unsigned*)(Hl + e * HL_STRIDE),
          16, 0, 17);
    }
    // prefetch gi + masks for this step (plain loads, overlap with DMA)
    unsigned gr[3], gz[3], gn[3];
    float mk[3];
#pragma unroll
    for (int j = 0; j < 3; ++j) {
      int idx = tid + j * 384;
      if (idx < 1024) {
        int e = idx >> 5, cp = (idx & 31) << 1;
        const unsigned short* gp2 =
            gi + ((size_t)(t * 512 + eb + e) * 1536 + cb + cp);
        gr[j] = *(const unsigned*)gp2;
        gz[j] = *(const unsigned*)(gp2 + 512);
        gn[j] = *(const unsigned*)(gp2 + 1024);
        mk[j] = masks[t * 512 + eb + e];
      }
    }
    __syncthreads();   // S1: Hl ready

    // gh = Hl(32x512) @ Wslice^T (unmasked h; mask folded in afterwards)
    f32x16 acc = {0.f, 0.f, 0.f, 0.f, 0.f, 0.f, 0.f, 0.f,
                  0.f, 0.f, 0.f, 0.f, 0.f, 0.f, 0.f, 0.f};
    const unsigned short* ap = Hl + l32 * HL_STRIDE + lhi * 8;
#pragma unroll
    for (int ks = 0; ks < 32; ++ks) {
      bf16x8 a = *(const bf16x8*)(ap + (ks << 4));
      acc = __builtin_amdgcn_mfma_f32_32x32x16_bf16(a, wreg[ks], acc, 0, 0, 0);
    }
    {
      float* gt = gatesL + gate * 2048 + half * 32;
#pragma unroll
      for (int reg = 0; reg < 16; ++reg) {
        int erow = (reg & 3) + 8 * (reg >> 2) + 4 * lhi;   // verified C/D layout
        gt[erow * 64 + l32] = acc[reg];
      }
    }
    __syncthreads();   // S2: gatesL ready

    // gates + h update
#pragma unroll
    for (int j = 0; j < 3; ++j) {
      int idx = tid + j * 384;
      if (idx < 1024) {
        int e = idx >> 5, cp = (idx & 31) << 1;
        float m = mk[j];
        int o = e * 64 + cp;
        float r0 = sigm(bf2f((unsigned short)gr[j]) + m * gatesL[o]);
        float r1 = sigm(bf2f((unsigned short)(gr[j] >> 16)) + m * gatesL[o + 1]);
        float z0 = sigm(bf2f((unsigned short)gz[j]) + m * gatesL[2048 + o]);
        float z1 = sigm(bf2f((unsigned short)(gz[j] >> 16)) + m * gatesL[2048 + o + 1]);
        float n0 = tanh_fast(bf2f((unsigned short)gn[j]) +
                             r0 * (m * gatesL[4096 + o] + bn0[j]));
        float n1 = tanh_fast(bf2f((unsigned short)(gn[j] >> 16)) +
                             r1 * (m * gatesL[4096 + o + 1] + bn1[j]));
        float h0 = hr0[j] * m;
        float h1 = hr1[j] * m;
        float hn0 = (1.0f - z0) * n0 + z0 * h0;
        float hn1 = (1.0f - z1) * n1 + z1 * h1;
        hr0[j] = hn0; hr1[j] = hn1;
        float2 ov; ov.x = hn0; ov.y = hn1;
        *(float2*)(out + ((size_t)(t * 512 + eb + e)) * 512 + cb + cp) = ov;
        unsigned pk = (unsigned)f2bf(hn0) | ((unsigned)f2bf(hn1) << 16);
        __hip_atomic_store(hbu + hdst + ((((unsigned)(eb + e) << 9) + cb + cp) >> 1),
                           pk, __ATOMIC_RELAXED, __HIP_MEMORY_SCOPE_AGENT);
        if (t == 127) {
          *(float2*)(out + (size_t)33554432 + (size_t)(eb + e) * 512 + cb + cp) = ov;
        }
      }
    }
    GROUP_BARRIER();   // step-t publishes visible before staging t+1
  }
#undef GROUP_BARRIER
}

// ---------------------------------------------------------------------------
// In-place LayerNorm over 65536 rows of 512 (one wave per row).
__global__ __launch_bounds__(256) void ln_kernel(float* __restrict__ out,
                                                 const float* __restrict__ lnw,
                                                 const float* __restrict__ lnb) {
  int row = blockIdx.x * 4 + (threadIdx.x >> 6);
  int lane = threadIdx.x & 63;
  float* p = out + (size_t)row * 512 + lane * 8;
  float4 v0 = *(float4*)p;
  float4 v1 = *(float4*)(p + 4);
  float s = v0.x + v0.y + v0.z + v0.w + v1.x + v1.y + v1.z + v1.w;
  float q = v0.x * v0.x + v0.y * v0.y + v0.z * v0.z + v0.w * v0.w +
            v1.x * v1.x + v1.y * v1.y + v1.z * v1.z + v1.w * v1.w;
#pragma unroll
  for (int m = 1; m < 64; m <<= 1) {
    s += __shfl_xor(s, m, 64);
    q += __shfl_xor(q, m, 64);
  }
  float mean = s * (1.0f / 512.0f);
  float var = q * (1.0f / 512.0f) - mean * mean;
  float rstd = rsqrtf(fmaxf(var, 0.0f) + 1e-5f);
  float4 w0 = *(const float4*)(lnw + lane * 8);
  float4 w1 = *(const float4*)(lnw + lane * 8 + 4);
  float4 b0 = *(const float4*)(lnb + lane * 8);
  float4 b1 = *(const float4*)(lnb + lane * 8 + 4);
  v0.x = (v0.x - mean) * rstd * w0.x + b0.x;
  v0.y = (v0.y - mean) * rstd * w0.y + b0.y;
  v0.z = (v0.z - mean) * rstd * w0.z + b0.z;
  v0.w = (v0.w - mean) * rstd * w0.w + b0.w;
  v1.x = (v1.x - mean) * rstd * w1.x + b1.x;
  v1.y = (v1.y - mean) * rstd * w1.y + b1.y;
  v1.z = (v1.z - mean) * rstd * w1.z + b1.z;
  v1.w = (v1.w - mean) * rstd * w1.w + b1.w;
  *(float4*)p = v0;
  *(float4*)(p + 4) = v1;
}

// ---------------------------------------------------------------------------
extern "C" void kernel_launch(void* const* d_in, const int* in_sizes, int n_in,
                              void* d_out, int out_size, void* d_ws, size_t ws_size,
                              hipStream_t stream) {
  const float* x    = (const float*)d_in[0];
  const float* hxs  = (const float*)d_in[1];
  const float* masks= (const float*)d_in[2];
  const float* wih  = (const float*)d_in[3];
  const float* whh  = (const float*)d_in[4];
  const float* bih  = (const float*)d_in[5];
  const float* bhh  = (const float*)d_in[6];
  const float* lnw  = (const float*)d_in[7];
  const float* lnb  = (const float*)d_in[8];
  float* out = (float*)d_out;
  char* ws = (char*)d_ws;

  unsigned short* gi     = (unsigned short*)ws;
  unsigned short* whh_bf = (unsigned short*)(ws + WHH_OFF);
  unsigned short* hb     = (unsigned short*)(ws + HB_OFF);
  unsigned int*   cnt    = (unsigned int*)(ws + CNT_OFF);

  prep_kernel<<<1024, 256, 0, stream>>>(whh, whh_bf, cnt);
  gi_gemm<<<dim3(512, 12), 256, 0, stream>>>(x, wih, bih, bhh, gi);
  rec_kernel<<<128, 384, 0, stream>>>(hxs, masks, bhh, gi, whh_bf, hb, cnt, out);
  ln_kernel<<<16384, 256, 0, stream>>>(out, lnw, lnb);
}